// Round 6
// baseline (429.385 us; speedup 1.0000x reference)
//
#include <hip/hip_runtime.h>

typedef __bf16 bf16;
typedef __attribute__((ext_vector_type(8))) __bf16 bf16x8;
typedef __attribute__((ext_vector_type(4))) __bf16 bf16x4;
typedef __attribute__((ext_vector_type(2))) __bf16 bf16x2;
typedef __attribute__((ext_vector_type(4))) float f32x4;

#define DEVINL __device__ __forceinline__

// Async global->LDS, 16B per lane.
DEVINL void gload_lds16(const bf16* g, bf16* l) {
    __builtin_amdgcn_global_load_lds(
        (__attribute__((address_space(1))) unsigned int*)(unsigned long long)g,
        (__attribute__((address_space(3))) unsigned int*)l,
        16, 0, 0);
}

// XCD-aware swizzle (uniform work): contiguous by-slab per XCD, bx fastest.
// Requires gridDim.y % 8 == 0.
DEVINL void xcd_swizzle(int& bx, int& by) {
    const int gx = gridDim.x, gy = gridDim.y;
    const int l = blockIdx.y * gx + blockIdx.x;
    const int xcd = l & 7;
    const int li = l >> 3;
    by = xcd * (gy >> 3) + li / gx;
    bx = li - (li / gx) * gx;
}

// Balanced XCD swizzle for causal grids (work ∝ by+1), gridDim.y==16 only:
// XCD x owns by = x and by = 15-x  ->  equal live work per XCD.
DEVINL void xcd_swizzle_bal(int& bx, int& by) {
    const int gx = gridDim.x, gy = gridDim.y;
    const int l = blockIdx.y * gx + blockIdx.x;
    const int xcd = l & 7;
    const int li = l >> 3;
    const int j = li / gx;            // slab 0 or 1
    bx = li - j * gx;
    by = j ? (gy - 1 - xcd) : xcd;
}

// ---------------------------------------------------------------- converts
// (weights only; activations are consumed in f32 by the proj GEMM)
__global__ __launch_bounds__(256) void cvt4_f32_to_bf16(
    const float* __restrict__ a, const float* __restrict__ b,
    const float* __restrict__ c, const float* __restrict__ d,
    bf16* __restrict__ out, int n4) {
    int i = blockIdx.x * blockDim.x + threadIdx.x;
    if (i >= n4) return;
    const float* src = (blockIdx.z == 0) ? a : (blockIdx.z == 1) ? b
                     : (blockIdx.z == 2) ? c : d;
    bf16* dst = out + (size_t)blockIdx.z * (size_t)n4 * 4;
    float4 f = ((const float4*)src)[i];
    bf16x4 o;
    o.x = (bf16)f.x; o.y = (bf16)f.y; o.z = (bf16)f.z; o.w = (bf16)f.w;
    ((bf16x4*)dst)[i] = o;
}

// ---------------------------------------------------------------- transpose
__global__ __launch_bounds__(256) void transpose_bf16(
    const unsigned short* __restrict__ in, unsigned short* __restrict__ out,
    int R, int C) {
    __shared__ unsigned short t[64][65];
    const size_t bo = (size_t)blockIdx.z * R * C;
    const int r0 = blockIdx.y * 64, c0 = blockIdx.x * 64;
    const int tr = threadIdx.x >> 4;      // 0..15
    const int tc = threadIdx.x & 15;      // 0..15
#pragma unroll
    for (int i = 0; i < 4; i++) {
        int r = tr + i * 16;
        ushort4 v = *(const ushort4*)&in[bo + (size_t)(r0 + r) * C + (c0 + tc * 4)];
        t[r][tc * 4 + 0] = v.x; t[r][tc * 4 + 1] = v.y;
        t[r][tc * 4 + 2] = v.z; t[r][tc * 4 + 3] = v.w;
    }
    __syncthreads();
#pragma unroll
    for (int i = 0; i < 4; i++) {
        int r = tr + i * 16;              // output row = original col
        ushort4 v;
        v.x = t[tc * 4 + 0][r]; v.y = t[tc * 4 + 1][r];
        v.z = t[tc * 4 + 2][r]; v.w = t[tc * 4 + 3][r];
        *(ushort4*)&out[bo + (size_t)(c0 + r) * R + (r0 + tc * 4)] = v;
    }
}

// ---------------------------------------------------------------- bias fold
// bout[e] = dot(Wo[e,:], bv) + bo[e]   (one wave per e)
__global__ __launch_bounds__(256) void bias_fold(
    const float* __restrict__ Wo, const float* __restrict__ bv,
    const float* __restrict__ bo, float* __restrict__ bout) {
    const int e = blockIdx.x * 4 + (threadIdx.x >> 6);
    const int lane = threadIdx.x & 63;
    float s = 0.f;
    for (int k = lane; k < 1024; k += 64) s += Wo[e * 1024 + k] * bv[k];
#pragma unroll
    for (int off = 32; off > 0; off >>= 1) s += __shfl_xor(s, off, 64);
    if (lane == 0) bout[e] = s + bo[e];
}

// ------------------------------- GEMM 128x128, BK=32, LDS dbuf + XOR swizzle
// (small Wvo = Wo @ Wv 1024^3 GEMM; bf16 A)
__global__ __launch_bounds__(256) void gemm_bt128(
    const bf16* __restrict__ A, const bf16* __restrict__ B,
    bf16* __restrict__ C, int M, int N, int K) {
    int bx, by;
    xcd_swizzle(bx, by);
    const int m0 = by * 128, n0 = bx * 128;

    __shared__ __align__(16) bf16 As[2][128 * 32];
    __shared__ __align__(16) bf16 Bs[2][128 * 32];

    const int tid = threadIdx.x;
    const int wave = tid >> 6;
    const int lane = tid & 63;
    const int lr = lane & 15;
    const int lq = lane >> 4;
    const int wm = (wave >> 1) * 64;
    const int wn = (wave & 1) * 64;
    const int srow = lane >> 2;
    const int scol = ((lane & 3) ^ ((lane >> 3) & 3)) * 8;

    const bf16* gA = A + (size_t)(m0 + wave * 16 + srow) * K + scol;
    const bf16* gB = B + (size_t)(n0 + wave * 16 + srow) * K + scol;
    const size_t rowskip = (size_t)64 * K;
    const int rsw = (lq ^ ((lr >> 1) & 3)) * 8;

    f32x4 acc[4][4];
    const f32x4 fzero = {0.f, 0.f, 0.f, 0.f};
#pragma unroll
    for (int i = 0; i < 4; i++)
#pragma unroll
        for (int j = 0; j < 4; j++) acc[i][j] = fzero;

#define STAGE128(bufi)                                          \
    do {                                                        \
        gload_lds16(gA,           As[bufi] + wave * 512);       \
        gload_lds16(gA + rowskip, As[bufi] + (wave + 4) * 512); \
        gload_lds16(gB,           Bs[bufi] + wave * 512);       \
        gload_lds16(gB + rowskip, Bs[bufi] + (wave + 4) * 512); \
        gA += 32; gB += 32;                                     \
    } while (0)

    STAGE128(0);
    int cur = 0;
    for (int k0 = 0; k0 < K; k0 += 32) {
        __syncthreads();
        if (k0 + 32 < K) STAGE128(cur ^ 1);

        bf16x8 af[4], bfr[4];
#pragma unroll
        for (int i = 0; i < 4; i++)
            af[i] = *(const bf16x8*)(As[cur] + (wm + i * 16 + lr) * 32 + rsw);
#pragma unroll
        for (int j = 0; j < 4; j++)
            bfr[j] = *(const bf16x8*)(Bs[cur] + (wn + j * 16 + lr) * 32 + rsw);
#pragma unroll
        for (int i = 0; i < 4; i++)
#pragma unroll
            for (int j = 0; j < 4; j++)
                acc[i][j] = __builtin_amdgcn_mfma_f32_16x16x32_bf16(
                    af[i], bfr[j], acc[i][j], 0, 0, 0);
        cur ^= 1;
    }
#undef STAGE128

#pragma unroll
    for (int j = 0; j < 4; j++) {
        const int col = n0 + wn + j * 16 + lr;
#pragma unroll
        for (int i = 0; i < 4; i++) {
            const int rowb = m0 + wm + i * 16 + lq * 4;
#pragma unroll
            for (int r = 0; r < 4; r++)
                C[(size_t)(rowb + r) * N + col] = (bf16)acc[i][j][r];
        }
    }
}

// ---------------- Projection GEMM 128x128, BK=32, 2-buf; A read as f32 and
// converted in-flight (reg-stage: 2x float4+float4 -> cvt -> ds_write_b128;
// produces the EXACT LDS image of the DMA path: lane's 16B at
// base + lane*16, data = global granule (lane&3)^((lane>>3)&3)).
// B (weights) via global_load_lds.  Round-0 loop order:
//   sync -> STAGE(next) -> frag reads(cur) -> MFMA(cur).
// z=0: Q=q@Wq^T+bq; z=1: K=k@Wk^T+bk; z=2: VW=v@Wvo^T (no bias).
__global__ __launch_bounds__(256) void gemm_projf(
    const float* __restrict__ A0, const float* __restrict__ A1,
    const float* __restrict__ A2, const bf16* __restrict__ Bw,
    const float* __restrict__ bias0, const float* __restrict__ bias1,
    bf16* __restrict__ Cq, int M, int N, int K) {
    int bx, by;
    xcd_swizzle(bx, by);
    const int bz = blockIdx.z;
    const int m0 = by * 128, n0 = bx * 128;

    const float* Af = (bz == 0) ? A0 : (bz == 1) ? A1 : A2;
    const bf16* B = Bw + (size_t)bz * (size_t)N * K;
    const float* bias = (bz == 0) ? bias0 : (bz == 1) ? bias1 : nullptr;
    bf16* C = Cq + (size_t)bz * (size_t)M * N;

    __shared__ __align__(16) bf16 As[2][128 * 32];
    __shared__ __align__(16) bf16 Bs[2][128 * 32];

    const int tid = threadIdx.x;
    const int wave = tid >> 6;
    const int lane = tid & 63;
    const int lr = lane & 15;
    const int lq = lane >> 4;
    const int wm = (wave >> 1) * 64;
    const int wn = (wave & 1) * 64;
    const int srow = lane >> 2;                       // 0..15
    const int gsrc = (lane & 3) ^ ((lane >> 3) & 3);  // pre-swizzled granule

    const float* fA = Af + (size_t)(m0 + wave * 16 + srow) * K + gsrc * 8;
    const bf16*  gB = B + (size_t)(n0 + wave * 16 + srow) * K + gsrc * 8;
    const size_t rsA = (size_t)64 * K;
    const size_t rsB = (size_t)64 * K;
    const int rsw = (lq ^ ((lr >> 1) & 3)) * 8;

    f32x4 acc[4][4];
    const f32x4 fzero = {0.f, 0.f, 0.f, 0.f};
#pragma unroll
    for (int i = 0; i < 4; i++)
#pragma unroll
        for (int j = 0; j < 4; j++) acc[i][j] = fzero;

#define STGP(bufi)                                                        \
    do {                                                                  \
        float4 a00 = *(const float4*)(fA);                                \
        float4 a01 = *(const float4*)(fA + 4);                            \
        float4 a10 = *(const float4*)(fA + rsA);                          \
        float4 a11 = *(const float4*)(fA + rsA + 4);                      \
        gload_lds16(gB,       Bs[bufi] + wave * 512);                     \
        gload_lds16(gB + rsB, Bs[bufi] + (wave + 4) * 512);               \
        bf16x8 p0, p1;                                                    \
        p0[0] = (bf16)a00.x; p0[1] = (bf16)a00.y;                         \
        p0[2] = (bf16)a00.z; p0[3] = (bf16)a00.w;                         \
        p0[4] = (bf16)a01.x; p0[5] = (bf16)a01.y;                         \
        p0[6] = (bf16)a01.z; p0[7] = (bf16)a01.w;                         \
        p1[0] = (bf16)a10.x; p1[1] = (bf16)a10.y;                         \
        p1[2] = (bf16)a10.z; p1[3] = (bf16)a10.w;                         \
        p1[4] = (bf16)a11.x; p1[5] = (bf16)a11.y;                         \
        p1[6] = (bf16)a11.z; p1[7] = (bf16)a11.w;                         \
        *(bf16x8*)(As[bufi] + wave * 512 + lane * 8) = p0;                \
        *(bf16x8*)(As[bufi] + (wave + 4) * 512 + lane * 8) = p1;          \
        fA += 32; gB += 32;                                               \
    } while (0)

    STGP(0);
    int cur = 0;
    for (int k0 = 0; k0 < K; k0 += 32) {
        __syncthreads();
        if (k0 + 32 < K) STGP(cur ^ 1);

        bf16x8 af[4], bfr[4];
#pragma unroll
        for (int i = 0; i < 4; i++)
            af[i] = *(const bf16x8*)(As[cur] + (wm + i * 16 + lr) * 32 + rsw);
#pragma unroll
        for (int j = 0; j < 4; j++)
            bfr[j] = *(const bf16x8*)(Bs[cur] + (wn + j * 16 + lr) * 32 + rsw);
#pragma unroll
        for (int i = 0; i < 4; i++)
#pragma unroll
            for (int j = 0; j < 4; j++)
                acc[i][j] = __builtin_amdgcn_mfma_f32_16x16x32_bf16(
                    af[i], bfr[j], acc[i][j], 0, 0, 0);
        cur ^= 1;
    }
#undef STGP

#pragma unroll
    for (int j = 0; j < 4; j++) {
        const int col = n0 + wn + j * 16 + lr;
        const float bb = bias ? bias[col] : 0.0f;
#pragma unroll
        for (int i = 0; i < 4; i++) {
            const int rowb = m0 + wm + i * 16 + lq * 4;
#pragma unroll
            for (int r = 0; r < 4; r++)
                C[(size_t)(rowb + r) * N + col] = (bf16)(acc[i][j][r] + bb);
        }
    }
}

// ---------------- Scores GEMM 128x64, BK=32 (round-0 structure, proven).
// Sc = Q K^T / 32 (bf16, raw; softmax handles causality). Skips tiles
// fully above the diagonal; balanced XCD swizzle for the causal grid.
__global__ __launch_bounds__(256) void gemm_sc(
    const bf16* __restrict__ Qb, const bf16* __restrict__ Kb,
    bf16* __restrict__ Sc, int S, int E) {
    int bx, by;
    xcd_swizzle_bal(bx, by);
    const int bz = blockIdx.z;
    const int m0 = by * 128, n0 = bx * 64;
    if (n0 > m0 + 127) return;

    const bf16* A = Qb + (size_t)bz * S * E;
    const bf16* B = Kb + (size_t)bz * S * E;

    __shared__ __align__(16) bf16 As[2][128 * 32];
    __shared__ __align__(16) bf16 Bs[2][64 * 32];

    const int tid = threadIdx.x;
    const int wave = tid >> 6;
    const int lane = tid & 63;
    const int lr = lane & 15;
    const int lq = lane >> 4;
    const int wm = wave * 32;
    const int srow = lane >> 2;
    const int scol = ((lane & 3) ^ ((lane >> 3) & 3)) * 8;

    const bf16* gA = A + (size_t)(m0 + wave * 16 + srow) * E + scol;
    const bf16* gB = B + (size_t)(n0 + wave * 16 + srow) * E + scol;
    const size_t rowskip = (size_t)64 * E;
    const int rsw = (lq ^ ((lr >> 1) & 3)) * 8;

    f32x4 acc[2][4];
    const f32x4 fzero = {0.f, 0.f, 0.f, 0.f};
#pragma unroll
    for (int i = 0; i < 2; i++)
#pragma unroll
        for (int j = 0; j < 4; j++) acc[i][j] = fzero;

#define STAGES(bufi)                                            \
    do {                                                        \
        gload_lds16(gA,           As[bufi] + wave * 512);       \
        gload_lds16(gA + rowskip, As[bufi] + (wave + 4) * 512); \
        gload_lds16(gB,           Bs[bufi] + wave * 512);       \
        gA += 32; gB += 32;                                     \
    } while (0)

    STAGES(0);
    int cur = 0;
    for (int k0 = 0; k0 < E; k0 += 32) {
        __syncthreads();
        if (k0 + 32 < E) STAGES(cur ^ 1);

        bf16x8 af[2], bfr[4];
#pragma unroll
        for (int i = 0; i < 2; i++)
            af[i] = *(const bf16x8*)(As[cur] + (wm + i * 16 + lr) * 32 + rsw);
#pragma unroll
        for (int j = 0; j < 4; j++)
            bfr[j] = *(const bf16x8*)(Bs[cur] + (j * 16 + lr) * 32 + rsw);
#pragma unroll
        for (int i = 0; i < 2; i++)
#pragma unroll
            for (int j = 0; j < 4; j++)
                acc[i][j] = __builtin_amdgcn_mfma_f32_16x16x32_bf16(
                    af[i], bfr[j], acc[i][j], 0, 0, 0);
        cur ^= 1;
    }
#undef STAGES

    bf16* dst = Sc + (size_t)bz * S * S;
#pragma unroll
    for (int j = 0; j < 4; j++) {
        const int col = n0 + j * 16 + lr;
#pragma unroll
        for (int i = 0; i < 2; i++) {
            const int rowb = m0 + wm + i * 16 + lq * 4;
#pragma unroll
            for (int r = 0; r < 4; r++)
                dst[(size_t)(rowb + r) * S + col] =
                    (bf16)(acc[i][j][r] * 0.03125f);
        }
    }
}

// ---------------------------------------------------------------- softmax
__global__ __launch_bounds__(256) void softmax_causal(
    const bf16* __restrict__ Sc, bf16* __restrict__ P, int S) {
    const int row = blockIdx.x;          // b*S + q
    const int q = row & (S - 1);
    const bf16* src = Sc + (size_t)row * S;
    bf16* dst = P + (size_t)row * S;
    const int L = q + 1;
    const int tid = threadIdx.x;
    const int k0 = tid * 8;

    bf16x8 u = ((const bf16x8*)src)[tid];
    float v[8];
    float mx = -3.0e38f;
#pragma unroll
    for (int i = 0; i < 8; i++) {
        v[i] = (k0 + i < L) ? (float)u[i] : -3.0e38f;
        mx = fmaxf(mx, v[i]);
    }
#pragma unroll
    for (int off = 32; off > 0; off >>= 1) mx = fmaxf(mx, __shfl_xor(mx, off, 64));
    __shared__ float redm[4], reds[4];
    if ((tid & 63) == 0) redm[tid >> 6] = mx;
    __syncthreads();
    mx = fmaxf(fmaxf(redm[0], redm[1]), fmaxf(redm[2], redm[3]));

    float sum = 0.f;
#pragma unroll
    for (int i = 0; i < 8; i++) {
        float e = (v[i] > -1.0e38f) ? __expf(v[i] - mx) : 0.f;
        v[i] = e;
        sum += e;
    }
#pragma unroll
    for (int off = 32; off > 0; off >>= 1) sum += __shfl_xor(sum, off, 64);
    if ((tid & 63) == 0) reds[tid >> 6] = sum;
    __syncthreads();
    sum = reds[0] + reds[1] + reds[2] + reds[3];
    const float inv = 1.0f / sum;
    bf16x8 o;
#pragma unroll
    for (int i = 0; i < 8; i++) o[i] = (bf16)(v[i] * inv);
    ((bf16x8*)dst)[tid] = o;
}

// ---------------- GEMM 128x128, BK=32, 256 thr, 4-buf template-phase pipe
// (proven round 3/4). 64 KiB LDS -> 2 blocks/CU so causal K-trimmed blocks
// pair on a CU. PV: Keff = m0+128; balanced pair swizzle.
__global__ __launch_bounds__(256, 2) void gemm_pv128(
    const bf16* __restrict__ A, const bf16* __restrict__ B,
    const float* __restrict__ bias, float* __restrict__ C,
    int M, int N, int K,
    long long sA, long long sB, long long sC,
    float scale) {
    int bx, by;
    xcd_swizzle_bal(bx, by);
    const int bz = blockIdx.z;
    const int m0 = by * 128, n0 = bx * 128;
    int Keff = m0 + 128; if (Keff > K) Keff = K;
    const int NT = Keff >> 5;   // >= 4

    A += (size_t)bz * sA;
    B += (size_t)bz * sB;

    __shared__ __align__(16) bf16 As[4][128 * 32];
    __shared__ __align__(16) bf16 Bs[4][128 * 32];

    const int tid = threadIdx.x;
    const int wave = tid >> 6;            // 0..3
    const int lane = tid & 63;
    const int lr = lane & 15;
    const int lq = lane >> 4;
    const int wm = (wave >> 1) * 64;
    const int wn = (wave & 1) * 64;

    const int srow = lane >> 2;
    const int scol = ((lane & 3) ^ ((lane >> 3) & 3)) * 8;
    const bf16* gA = A + (size_t)(m0 + wave * 16 + srow) * K + scol;
    const bf16* gB = B + (size_t)(n0 + wave * 16 + srow) * K + scol;
    const size_t rowskip = (size_t)64 * K;

    const int rsw = (lq ^ ((lr >> 1) & 3)) * 8;

    f32x4 acc[4][4];
    const f32x4 fzero = {0.f, 0.f, 0.f, 0.f};
#pragma unroll
    for (int i = 0; i < 4; i++)
#pragma unroll
        for (int j = 0; j < 4; j++) acc[i][j] = fzero;

#define STAGEV(bufi, koff)                                                 \
    do {                                                                   \
        gload_lds16(gA + (koff),           As[bufi] + wave * 512);         \
        gload_lds16(gA + rowskip + (koff), As[bufi] + (wave + 4) * 512);   \
        gload_lds16(gB + (koff),           Bs[bufi] + wave * 512);         \
        gload_lds16(gB + rowskip + (koff), Bs[bufi] + (wave + 4) * 512);   \
    } while (0)

    STAGEV(0, 0);
    STAGEV(1, 32);
    STAGEV(2, 64);
    asm volatile("s_waitcnt vmcnt(8)" ::: "memory");
    __builtin_amdgcn_s_barrier();

    for (int t = 0; t < NT; ++t) {
        const int bfi = t & 3;

        bf16x8 af[4], bfr[4];
#pragma unroll
        for (int i = 0; i < 4; i++)
            af[i] = *(const bf16x8*)(As[bfi] + (wm + i * 16 + lr) * 32 + rsw);
#pragma unroll
        for (int j = 0; j < 4; j++)
            bfr[j] = *(const bf16x8*)(Bs[bfi] + (wn + j * 16 + lr) * 32 + rsw);

        if (t + 3 < NT) STAGEV((t + 3) & 3, (t + 3) * 32);

        const int rem = NT - 1 - t;
        if (rem >= 3)      asm volatile("s_waitcnt vmcnt(8)" ::: "memory");
        else if (rem == 2) asm volatile("s_waitcnt vmcnt(4)" ::: "memory");
        else if (rem == 1) asm volatile("s_waitcnt vmcnt(0)" ::: "memory");
        __builtin_amdgcn_s_barrier();
        __builtin_amdgcn_sched_barrier(0);

        __builtin_amdgcn_s_setprio(1);
#pragma unroll
        for (int i = 0; i < 4; i++)
#pragma unroll
            for (int j = 0; j < 4; j++)
                acc[i][j] = __builtin_amdgcn_mfma_f32_16x16x32_bf16(
                    af[i], bfr[j], acc[i][j], 0, 0, 0);
        __builtin_amdgcn_s_setprio(0);
        __builtin_amdgcn_s_barrier();
    }
#undef STAGEV

#pragma unroll
    for (int j = 0; j < 4; j++) {
        const int col = n0 + wn + j * 16 + lr;
        const float bb = bias[col];
#pragma unroll
        for (int i = 0; i < 4; i++) {
            const int rowb = m0 + wm + i * 16 + lq * 4;
#pragma unroll
            for (int r = 0; r < 4; r++)
                C[(size_t)bz * sC + (size_t)(rowb + r) * N + col] =
                    acc[i][j][r] * scale + bb;
        }
    }
}

// ---------------------------------------------------------------- launch
extern "C" void kernel_launch(void* const* d_in, const int* in_sizes, int n_in,
                              void* d_out, int out_size, void* d_ws, size_t ws_size,
                              hipStream_t stream) {
    const int B = 4, S = 2048, E = 1024;
    const size_t SBE = (size_t)B * S * E;   // 8,388,608
    const size_t EE = (size_t)E * E;        // 1,048,576
    const size_t BSS = (size_t)B * S * S;   // 16,777,216

    const float* q_in = (const float*)d_in[0];
    const float* k_in = (const float*)d_in[1];
    const float* v_in = (const float*)d_in[2];
    // d_in[3] = mask (tril) — causality handled by index math
    const float* Wq = (const float*)d_in[4];
    const float* bq = (const float*)d_in[5];
    const float* Wk = (const float*)d_in[6];
    const float* bk = (const float*)d_in[7];
    const float* Wv = (const float*)d_in[8];
    const float* bv = (const float*)d_in[9];
    const float* Wo = (const float*)d_in[10];
    const float* bo = (const float*)d_in[11];

    char* ws = (char*)d_ws;
    bf16* QKVb = (bf16*)ws;                                  // 48 MB Qb|Kb|VW
    bf16* VWt  = (bf16*)(ws + 3 * SBE * 2);                  // 16 MB
    bf16* Sc   = (bf16*)(ws + 4 * SBE * 2);                  // 33.5 MB
    bf16* Pb   = (bf16*)(ws + 4 * SBE * 2 + BSS * 2);        // 33.5 MB
    bf16* Wb   = (bf16*)(ws + 4 * SBE * 2 + 2 * BSS * 2);    // 8 MB
    bf16* WvT  = Wb + 4 * EE;                                // 2 MB
    float* bout = (float*)(WvT + EE);                        // 4 KB

    bf16* Qb = QKVb;
    bf16* Kb = QKVb + SBE;
    bf16* VW = QKVb + 2 * SBE;
    bf16* Wob = Wb + 3 * EE;
    bf16* Wvo = Wb + 2 * EE;   // Wv slot overwritten by Wvo after transpose

    dim3 blk(256);

    // 1. weight converts (activations consumed as f32 by gemm_projf)
    dim3 gcvt4((int)(EE / 4 / 256), 1, 4);
    cvt4_f32_to_bf16<<<gcvt4, blk, 0, stream>>>(Wq, Wk, Wv, Wo, Wb, (int)(EE / 4));

    // 2. WvT = Wv^T ; Wvo = Wo @ Wv ; bout = Wo bv + bo
    dim3 gtw(16, 16, 1);
    transpose_bf16<<<gtw, blk, 0, stream>>>((const unsigned short*)(Wb + 2 * EE),
                                            (unsigned short*)WvT, E, E);
    dim3 gwvo(E / 128, E / 128, 1);
    gemm_bt128<<<gwvo, blk, 0, stream>>>(Wob, WvT, Wvo, E, E, E);
    bias_fold<<<256, blk, 0, stream>>>(Wo, bv, bo, bout);

    // 3. fused projections from f32 inputs: Q, K, VW = v @ Wvo^T
    dim3 gproj(E / 128, (B * S) / 128, 3);
    gemm_projf<<<gproj, blk, 0, stream>>>(q_in, k_in, v_in, Wb, bq, bk,
                                          QKVb, B * S, E, E);

    // 4. VW^T per batch: [S,E] -> [E,S]
    dim3 gt(E / 64, S / 64, B);
    transpose_bf16<<<gt, blk, 0, stream>>>((const unsigned short*)VW,
                                           (unsigned short*)VWt, S, E);

    // 5. scores = Q K^T / 32 -> Sc bf16 (causal tile skip)
    dim3 gsc(S / 64, S / 128, B);
    gemm_sc<<<gsc, blk, 0, stream>>>(Qb, Kb, Sc, S, E);

    // 6. causal softmax -> bf16 probs (zeros above diagonal)
    softmax_causal<<<B * S, blk, 0, stream>>>(Sc, Pb, S);

    // 7. out = P @ VW + bout, causal K-trim (Keff = m0+128), 2 blocks/CU,
    //    XCD-pair-balanced
    dim3 gpv(E / 128, S / 128, B);
    gemm_pv128<<<gpv, blk, 0, stream>>>(Pb, VWt, bout, (float*)d_out, S, E, S,
                                        (long long)S * S, (long long)E * S,
                                        (long long)S * E, 1.f);
}

// Round 7
// 398.764 us; speedup vs baseline: 1.0768x; 1.0768x over previous
//
#include <hip/hip_runtime.h>

typedef __bf16 bf16;
typedef __attribute__((ext_vector_type(8))) __bf16 bf16x8;
typedef __attribute__((ext_vector_type(4))) __bf16 bf16x4;
typedef __attribute__((ext_vector_type(2))) __bf16 bf16x2;
typedef __attribute__((ext_vector_type(4))) float f32x4;

#define DEVINL __device__ __forceinline__

// Async global->LDS, 16B per lane.
DEVINL void gload_lds16(const bf16* g, bf16* l) {
    __builtin_amdgcn_global_load_lds(
        (__attribute__((address_space(1))) unsigned int*)(unsigned long long)g,
        (__attribute__((address_space(3))) unsigned int*)l,
        16, 0, 0);
}

// XCD-aware swizzle (uniform work): contiguous by-slab per XCD, bx fastest.
// Requires gridDim.y % 8 == 0.
DEVINL void xcd_swizzle(int& bx, int& by) {
    const int gx = gridDim.x, gy = gridDim.y;
    const int l = blockIdx.y * gx + blockIdx.x;
    const int xcd = l & 7;
    const int li = l >> 3;
    by = xcd * (gy >> 3) + li / gx;
    bx = li - (li / gx) * gx;
}

// Balanced XCD swizzle for causal grids (work ∝ by+1), gridDim.y==16 only:
// XCD x owns by = x and by = 15-x  ->  equal live work per XCD.
DEVINL void xcd_swizzle_bal(int& bx, int& by) {
    const int gx = gridDim.x, gy = gridDim.y;
    const int l = blockIdx.y * gx + blockIdx.x;
    const int xcd = l & 7;
    const int li = l >> 3;
    const int j = li / gx;            // slab 0 or 1
    bx = li - j * gx;
    by = j ? (gy - 1 - xcd) : xcd;
}

// ---------------------------------------------------------------- converts
// (weights only; activations are consumed in f32 by the proj GEMM)
__global__ __launch_bounds__(256) void cvt4_f32_to_bf16(
    const float* __restrict__ a, const float* __restrict__ b,
    const float* __restrict__ c, const float* __restrict__ d,
    bf16* __restrict__ out, int n4) {
    int i = blockIdx.x * blockDim.x + threadIdx.x;
    if (i >= n4) return;
    const float* src = (blockIdx.z == 0) ? a : (blockIdx.z == 1) ? b
                     : (blockIdx.z == 2) ? c : d;
    bf16* dst = out + (size_t)blockIdx.z * (size_t)n4 * 4;
    float4 f = ((const float4*)src)[i];
    bf16x4 o;
    o.x = (bf16)f.x; o.y = (bf16)f.y; o.z = (bf16)f.z; o.w = (bf16)f.w;
    ((bf16x4*)dst)[i] = o;
}

// ---------------------------------------------------------------- transpose
__global__ __launch_bounds__(256) void transpose_bf16(
    const unsigned short* __restrict__ in, unsigned short* __restrict__ out,
    int R, int C) {
    __shared__ unsigned short t[64][65];
    const size_t bo = (size_t)blockIdx.z * R * C;
    const int r0 = blockIdx.y * 64, c0 = blockIdx.x * 64;
    const int tr = threadIdx.x >> 4;      // 0..15
    const int tc = threadIdx.x & 15;      // 0..15
#pragma unroll
    for (int i = 0; i < 4; i++) {
        int r = tr + i * 16;
        ushort4 v = *(const ushort4*)&in[bo + (size_t)(r0 + r) * C + (c0 + tc * 4)];
        t[r][tc * 4 + 0] = v.x; t[r][tc * 4 + 1] = v.y;
        t[r][tc * 4 + 2] = v.z; t[r][tc * 4 + 3] = v.w;
    }
    __syncthreads();
#pragma unroll
    for (int i = 0; i < 4; i++) {
        int r = tr + i * 16;              // output row = original col
        ushort4 v;
        v.x = t[tc * 4 + 0][r]; v.y = t[tc * 4 + 1][r];
        v.z = t[tc * 4 + 2][r]; v.w = t[tc * 4 + 3][r];
        *(ushort4*)&out[bo + (size_t)(c0 + r) * R + (r0 + tc * 4)] = v;
    }
}

// ---------------------------------------------------------------- bias fold
// bout[e] = dot(Wo[e,:], bv) + bo[e]   (one wave per e)
__global__ __launch_bounds__(256) void bias_fold(
    const float* __restrict__ Wo, const float* __restrict__ bv,
    const float* __restrict__ bo, float* __restrict__ bout) {
    const int e = blockIdx.x * 4 + (threadIdx.x >> 6);
    const int lane = threadIdx.x & 63;
    float s = 0.f;
    for (int k = lane; k < 1024; k += 64) s += Wo[e * 1024 + k] * bv[k];
#pragma unroll
    for (int off = 32; off > 0; off >>= 1) s += __shfl_xor(s, off, 64);
    if (lane == 0) bout[e] = s + bo[e];
}

// ------------------------------- GEMM 128x128, BK=32, LDS dbuf + XOR swizzle
// (small Wvo = Wo @ Wv 1024^3 GEMM; bf16 A)
__global__ __launch_bounds__(256) void gemm_bt128(
    const bf16* __restrict__ A, const bf16* __restrict__ B,
    bf16* __restrict__ C, int M, int N, int K) {
    int bx, by;
    xcd_swizzle(bx, by);
    const int m0 = by * 128, n0 = bx * 128;

    __shared__ __align__(16) bf16 As[2][128 * 32];
    __shared__ __align__(16) bf16 Bs[2][128 * 32];

    const int tid = threadIdx.x;
    const int wave = tid >> 6;
    const int lane = tid & 63;
    const int lr = lane & 15;
    const int lq = lane >> 4;
    const int wm = (wave >> 1) * 64;
    const int wn = (wave & 1) * 64;
    const int srow = lane >> 2;
    const int scol = ((lane & 3) ^ ((lane >> 3) & 3)) * 8;

    const bf16* gA = A + (size_t)(m0 + wave * 16 + srow) * K + scol;
    const bf16* gB = B + (size_t)(n0 + wave * 16 + srow) * K + scol;
    const size_t rowskip = (size_t)64 * K;
    const int rsw = (lq ^ ((lr >> 1) & 3)) * 8;

    f32x4 acc[4][4];
    const f32x4 fzero = {0.f, 0.f, 0.f, 0.f};
#pragma unroll
    for (int i = 0; i < 4; i++)
#pragma unroll
        for (int j = 0; j < 4; j++) acc[i][j] = fzero;

#define STAGE128(bufi)                                          \
    do {                                                        \
        gload_lds16(gA,           As[bufi] + wave * 512);       \
        gload_lds16(gA + rowskip, As[bufi] + (wave + 4) * 512); \
        gload_lds16(gB,           Bs[bufi] + wave * 512);       \
        gload_lds16(gB + rowskip, Bs[bufi] + (wave + 4) * 512); \
        gA += 32; gB += 32;                                     \
    } while (0)

    STAGE128(0);
    int cur = 0;
    for (int k0 = 0; k0 < K; k0 += 32) {
        __syncthreads();
        if (k0 + 32 < K) STAGE128(cur ^ 1);

        bf16x8 af[4], bfr[4];
#pragma unroll
        for (int i = 0; i < 4; i++)
            af[i] = *(const bf16x8*)(As[cur] + (wm + i * 16 + lr) * 32 + rsw);
#pragma unroll
        for (int j = 0; j < 4; j++)
            bfr[j] = *(const bf16x8*)(Bs[cur] + (wn + j * 16 + lr) * 32 + rsw);
#pragma unroll
        for (int i = 0; i < 4; i++)
#pragma unroll
            for (int j = 0; j < 4; j++)
                acc[i][j] = __builtin_amdgcn_mfma_f32_16x16x32_bf16(
                    af[i], bfr[j], acc[i][j], 0, 0, 0);
        cur ^= 1;
    }
#undef STAGE128

#pragma unroll
    for (int j = 0; j < 4; j++) {
        const int col = n0 + wn + j * 16 + lr;
#pragma unroll
        for (int i = 0; i < 4; i++) {
            const int rowb = m0 + wm + i * 16 + lq * 4;
#pragma unroll
            for (int r = 0; r < 4; r++)
                C[(size_t)(rowb + r) * N + col] = (bf16)acc[i][j][r];
        }
    }
}

// ---------------- Projection GEMM 128x128, BK=32, 2-buf; A read as f32 with
// T14 issue-early/write-late split:
//   iter t: ds_read frags(buf cur) ; cvt+ds_write A(t+1)->buf cur^1 (regs
//   loaded at iter t-1, drained by the barrier) ; gload_lds B(t+1) ;
//   ISSUE f32 loads A(t+2) ; MFMA(t) ; __syncthreads (drains DMA+loads).
// The f32 load latency hides under MFMA + the barrier drain (same cost the
// DMA path already paid), instead of stalling cvt in-iteration (round-6 bug:
// 146us). LDS image identical to the DMA path. z=0:Q+bq z=1:K+bk z=2:VW.
__global__ __launch_bounds__(256) void gemm_projf(
    const float* __restrict__ A0, const float* __restrict__ A1,
    const float* __restrict__ A2, const bf16* __restrict__ Bw,
    const float* __restrict__ bias0, const float* __restrict__ bias1,
    bf16* __restrict__ Cq, int M, int N, int K) {
    int bx, by;
    xcd_swizzle(bx, by);
    const int bz = blockIdx.z;
    const int m0 = by * 128, n0 = bx * 128;

    const float* Af = (bz == 0) ? A0 : (bz == 1) ? A1 : A2;
    const bf16* B = Bw + (size_t)bz * (size_t)N * K;
    const float* bias = (bz == 0) ? bias0 : (bz == 1) ? bias1 : nullptr;
    bf16* C = Cq + (size_t)bz * (size_t)M * N;

    __shared__ __align__(16) bf16 As[2][128 * 32];
    __shared__ __align__(16) bf16 Bs[2][128 * 32];

    const int tid = threadIdx.x;
    const int wave = tid >> 6;
    const int lane = tid & 63;
    const int lr = lane & 15;
    const int lq = lane >> 4;
    const int wm = (wave >> 1) * 64;
    const int wn = (wave & 1) * 64;
    const int srow = lane >> 2;                       // 0..15
    const int gsrc = (lane & 3) ^ ((lane >> 3) & 3);  // pre-swizzled granule

    const float* fA = Af + (size_t)(m0 + wave * 16 + srow) * K + gsrc * 8;
    const bf16*  gB = B + (size_t)(n0 + wave * 16 + srow) * K + gsrc * 8;
    const size_t rsA = (size_t)64 * K;
    const size_t rsB = (size_t)64 * K;
    const int rsw = (lq ^ ((lr >> 1) & 3)) * 8;
    const int NT = K >> 5;    // 32

    f32x4 acc[4][4];
    const f32x4 fzero = {0.f, 0.f, 0.f, 0.f};
#pragma unroll
    for (int i = 0; i < 4; i++)
#pragma unroll
        for (int j = 0; j < 4; j++) acc[i][j] = fzero;

    float4 a00, a01, a10, a11;   // in-flight A registers (one tile)

#define LOADA(kt)                                                         \
    do {                                                                  \
        const float* p_ = fA + (size_t)(kt) * 32;                         \
        a00 = *(const float4*)(p_);                                       \
        a01 = *(const float4*)(p_ + 4);                                   \
        a10 = *(const float4*)(p_ + rsA);                                 \
        a11 = *(const float4*)(p_ + rsA + 4);                             \
    } while (0)
#define WRITEA(bufi)                                                      \
    do {                                                                  \
        bf16x8 p0, p1;                                                    \
        p0[0] = (bf16)a00.x; p0[1] = (bf16)a00.y;                         \
        p0[2] = (bf16)a00.z; p0[3] = (bf16)a00.w;                         \
        p0[4] = (bf16)a01.x; p0[5] = (bf16)a01.y;                         \
        p0[6] = (bf16)a01.z; p0[7] = (bf16)a01.w;                         \
        p1[0] = (bf16)a10.x; p1[1] = (bf16)a10.y;                         \
        p1[2] = (bf16)a10.z; p1[3] = (bf16)a10.w;                         \
        p1[4] = (bf16)a11.x; p1[5] = (bf16)a11.y;                         \
        p1[6] = (bf16)a11.z; p1[7] = (bf16)a11.w;                         \
        *(bf16x8*)(As[bufi] + wave * 512 + lane * 8) = p0;                \
        *(bf16x8*)(As[bufi] + (wave + 4) * 512 + lane * 8) = p1;          \
    } while (0)
#define STAGEB(bufi, kt)                                                  \
    do {                                                                  \
        gload_lds16(gB + (size_t)(kt) * 32,       Bs[bufi] + wave * 512); \
        gload_lds16(gB + rsB + (size_t)(kt) * 32, Bs[bufi] + (wave + 4) * 512); \
    } while (0)

    // prologue: A(0) loaded+written, B(0) staged, A(1) issued; barrier drains.
    LOADA(0);
    STAGEB(0, 0);
    WRITEA(0);       // compiler inserts vmcnt wait for a00..a11 (once)
    LOADA(1);        // in flight across the barrier
    __syncthreads();

    int cur = 0;
    for (int t = 0; t < NT; ++t) {
        bf16x8 af[4], bfr[4];
#pragma unroll
        for (int i = 0; i < 4; i++)
            af[i] = *(const bf16x8*)(As[cur] + (wm + i * 16 + lr) * 32 + rsw);
#pragma unroll
        for (int j = 0; j < 4; j++)
            bfr[j] = *(const bf16x8*)(Bs[cur] + (wn + j * 16 + lr) * 32 + rsw);

        if (t + 1 < NT) {
            WRITEA(cur ^ 1);              // A(t+1): regs resident (barrier)
            STAGEB(cur ^ 1, t + 1);       // B(t+1) DMA
            if (t + 2 < NT) LOADA(t + 2); // issue A(t+2), drained at barrier
        }

#pragma unroll
        for (int i = 0; i < 4; i++)
#pragma unroll
            for (int j = 0; j < 4; j++)
                acc[i][j] = __builtin_amdgcn_mfma_f32_16x16x32_bf16(
                    af[i], bfr[j], acc[i][j], 0, 0, 0);
        __syncthreads();
        cur ^= 1;
    }
#undef LOADA
#undef WRITEA
#undef STAGEB

#pragma unroll
    for (int j = 0; j < 4; j++) {
        const int col = n0 + wn + j * 16 + lr;
        const float bb = bias ? bias[col] : 0.0f;
#pragma unroll
        for (int i = 0; i < 4; i++) {
            const int rowb = m0 + wm + i * 16 + lq * 4;
#pragma unroll
            for (int r = 0; r < 4; r++)
                C[(size_t)(rowb + r) * N + col] = (bf16)(acc[i][j][r] + bb);
        }
    }
}

// ---------------- Scores GEMM 128x128 (proven bt128 body) + causal skip.
// Sc = Q K^T / 32 (bf16 raw; softmax handles masking). 544 live blocks of
// 1024; balanced XCD swizzle (gy=16) pairs by=x with by=15-x.
__global__ __launch_bounds__(256) void gemm_sc128(
    const bf16* __restrict__ Qb, const bf16* __restrict__ Kb,
    bf16* __restrict__ Sc, int S, int E) {
    int bx, by;
    xcd_swizzle_bal(bx, by);
    const int bz = blockIdx.z;
    const int m0 = by * 128, n0 = bx * 128;
    if (n0 > m0 + 127) return;   // fully above diagonal

    const bf16* A = Qb + (size_t)bz * S * E;
    const bf16* B = Kb + (size_t)bz * S * E;

    __shared__ __align__(16) bf16 As[2][128 * 32];
    __shared__ __align__(16) bf16 Bs[2][128 * 32];

    const int tid = threadIdx.x;
    const int wave = tid >> 6;
    const int lane = tid & 63;
    const int lr = lane & 15;
    const int lq = lane >> 4;
    const int wm = (wave >> 1) * 64;
    const int wn = (wave & 1) * 64;
    const int srow = lane >> 2;
    const int scol = ((lane & 3) ^ ((lane >> 3) & 3)) * 8;

    const bf16* gA = A + (size_t)(m0 + wave * 16 + srow) * E + scol;
    const bf16* gB = B + (size_t)(n0 + wave * 16 + srow) * E + scol;
    const size_t rowskip = (size_t)64 * E;
    const int rsw = (lq ^ ((lr >> 1) & 3)) * 8;

    f32x4 acc[4][4];
    const f32x4 fzero = {0.f, 0.f, 0.f, 0.f};
#pragma unroll
    for (int i = 0; i < 4; i++)
#pragma unroll
        for (int j = 0; j < 4; j++) acc[i][j] = fzero;

#define STAGESC(bufi)                                           \
    do {                                                        \
        gload_lds16(gA,           As[bufi] + wave * 512);       \
        gload_lds16(gA + rowskip, As[bufi] + (wave + 4) * 512); \
        gload_lds16(gB,           Bs[bufi] + wave * 512);       \
        gload_lds16(gB + rowskip, Bs[bufi] + (wave + 4) * 512); \
        gA += 32; gB += 32;                                     \
    } while (0)

    STAGESC(0);
    int cur = 0;
    for (int k0 = 0; k0 < E; k0 += 32) {
        __syncthreads();
        if (k0 + 32 < E) STAGESC(cur ^ 1);

        bf16x8 af[4], bfr[4];
#pragma unroll
        for (int i = 0; i < 4; i++)
            af[i] = *(const bf16x8*)(As[cur] + (wm + i * 16 + lr) * 32 + rsw);
#pragma unroll
        for (int j = 0; j < 4; j++)
            bfr[j] = *(const bf16x8*)(Bs[cur] + (wn + j * 16 + lr) * 32 + rsw);
#pragma unroll
        for (int i = 0; i < 4; i++)
#pragma unroll
            for (int j = 0; j < 4; j++)
                acc[i][j] = __builtin_amdgcn_mfma_f32_16x16x32_bf16(
                    af[i], bfr[j], acc[i][j], 0, 0, 0);
        cur ^= 1;
    }
#undef STAGESC

    bf16* dst = Sc + (size_t)bz * S * S;
#pragma unroll
    for (int j = 0; j < 4; j++) {
        const int col = n0 + wn + j * 16 + lr;
#pragma unroll
        for (int i = 0; i < 4; i++) {
            const int rowb = m0 + wm + i * 16 + lq * 4;
#pragma unroll
            for (int r = 0; r < 4; r++)
                dst[(size_t)(rowb + r) * S + col] =
                    (bf16)(acc[i][j][r] * 0.03125f);
        }
    }
}

// ---------------------------------------------------------------- softmax
__global__ __launch_bounds__(256) void softmax_causal(
    const bf16* __restrict__ Sc, bf16* __restrict__ P, int S) {
    const int row = blockIdx.x;          // b*S + q
    const int q = row & (S - 1);
    const bf16* src = Sc + (size_t)row * S;
    bf16* dst = P + (size_t)row * S;
    const int L = q + 1;
    const int tid = threadIdx.x;
    const int k0 = tid * 8;

    bf16x8 u = ((const bf16x8*)src)[tid];
    float v[8];
    float mx = -3.0e38f;
#pragma unroll
    for (int i = 0; i < 8; i++) {
        v[i] = (k0 + i < L) ? (float)u[i] : -3.0e38f;
        mx = fmaxf(mx, v[i]);
    }
#pragma unroll
    for (int off = 32; off > 0; off >>= 1) mx = fmaxf(mx, __shfl_xor(mx, off, 64));
    __shared__ float redm[4], reds[4];
    if ((tid & 63) == 0) redm[tid >> 6] = mx;
    __syncthreads();
    mx = fmaxf(fmaxf(redm[0], redm[1]), fmaxf(redm[2], redm[3]));

    float sum = 0.f;
#pragma unroll
    for (int i = 0; i < 8; i++) {
        float e = (v[i] > -1.0e38f) ? __expf(v[i] - mx) : 0.f;
        v[i] = e;
        sum += e;
    }
#pragma unroll
    for (int off = 32; off > 0; off >>= 1) sum += __shfl_xor(sum, off, 64);
    if ((tid & 63) == 0) reds[tid >> 6] = sum;
    __syncthreads();
    sum = reds[0] + reds[1] + reds[2] + reds[3];
    const float inv = 1.0f / sum;
    bf16x8 o;
#pragma unroll
    for (int i = 0; i < 8; i++) o[i] = (bf16)(v[i] * inv);
    ((bf16x8*)dst)[tid] = o;
}

// ---------------- GEMM 128x128, BK=32, 256 thr, 4-buf template-phase pipe
// (proven round 3/4/6). 64 KiB LDS -> 2 blocks/CU so causal K-trimmed blocks
// pair on a CU. PV: Keff = m0+128; balanced pair swizzle.
__global__ __launch_bounds__(256, 2) void gemm_pv128(
    const bf16* __restrict__ A, const bf16* __restrict__ B,
    const float* __restrict__ bias, float* __restrict__ C,
    int M, int N, int K,
    long long sA, long long sB, long long sC,
    float scale) {
    int bx, by;
    xcd_swizzle_bal(bx, by);
    const int bz = blockIdx.z;
    const int m0 = by * 128, n0 = bx * 128;
    int Keff = m0 + 128; if (Keff > K) Keff = K;
    const int NT = Keff >> 5;   // >= 4

    A += (size_t)bz * sA;
    B += (size_t)bz * sB;

    __shared__ __align__(16) bf16 As[4][128 * 32];
    __shared__ __align__(16) bf16 Bs[4][128 * 32];

    const int tid = threadIdx.x;
    const int wave = tid >> 6;            // 0..3
    const int lane = tid & 63;
    const int lr = lane & 15;
    const int lq = lane >> 4;
    const int wm = (wave >> 1) * 64;
    const int wn = (wave & 1) * 64;

    const int srow = lane >> 2;
    const int scol = ((lane & 3) ^ ((lane >> 3) & 3)) * 8;
    const bf16* gA = A + (size_t)(m0 + wave * 16 + srow) * K + scol;
    const bf16* gB = B + (size_t)(n0 + wave * 16 + srow) * K + scol;
    const size_t rowskip = (size_t)64 * K;

    const int rsw = (lq ^ ((lr >> 1) & 3)) * 8;

    f32x4 acc[4][4];
    const f32x4 fzero = {0.f, 0.f, 0.f, 0.f};
#pragma unroll
    for (int i = 0; i < 4; i++)
#pragma unroll
        for (int j = 0; j < 4; j++) acc[i][j] = fzero;

#define STAGEV(bufi, koff)                                                 \
    do {                                                                   \
        gload_lds16(gA + (koff),           As[bufi] + wave * 512);         \
        gload_lds16(gA + rowskip + (koff), As[bufi] + (wave + 4) * 512);   \
        gload_lds16(gB + (koff),           Bs[bufi] + wave * 512);         \
        gload_lds16(gB + rowskip + (koff), Bs[bufi] + (wave + 4) * 512);   \
    } while (0)

    STAGEV(0, 0);
    STAGEV(1, 32);
    STAGEV(2, 64);
    asm volatile("s_waitcnt vmcnt(8)" ::: "memory");
    __builtin_amdgcn_s_barrier();

    for (int t = 0; t < NT; ++t) {
        const int bfi = t & 3;

        bf16x8 af[4], bfr[4];
#pragma unroll
        for (int i = 0; i < 4; i++)
            af[i] = *(const bf16x8*)(As[bfi] + (wm + i * 16 + lr) * 32 + rsw);
#pragma unroll
        for (int j = 0; j < 4; j++)
            bfr[j] = *(const bf16x8*)(Bs[bfi] + (wn + j * 16 + lr) * 32 + rsw);

        if (t + 3 < NT) STAGEV((t + 3) & 3, (t + 3) * 32);

        const int rem = NT - 1 - t;
        if (rem >= 3)      asm volatile("s_waitcnt vmcnt(8)" ::: "memory");
        else if (rem == 2) asm volatile("s_waitcnt vmcnt(4)" ::: "memory");
        else if (rem == 1) asm volatile("s_waitcnt vmcnt(0)" ::: "memory");
        __builtin_amdgcn_s_barrier();
        __builtin_amdgcn_sched_barrier(0);

        __builtin_amdgcn_s_setprio(1);
#pragma unroll
        for (int i = 0; i < 4; i++)
#pragma unroll
            for (int j = 0; j < 4; j++)
                acc[i][j] = __builtin_amdgcn_mfma_f32_16x16x32_bf16(
                    af[i], bfr[j], acc[i][j], 0, 0, 0);
        __builtin_amdgcn_s_setprio(0);
        __builtin_amdgcn_s_barrier();
    }
#undef STAGEV

#pragma unroll
    for (int j = 0; j < 4; j++) {
        const int col = n0 + wn + j * 16 + lr;
        const float bb = bias[col];
#pragma unroll
        for (int i = 0; i < 4; i++) {
            const int rowb = m0 + wm + i * 16 + lq * 4;
#pragma unroll
            for (int r = 0; r < 4; r++)
                C[(size_t)bz * sC + (size_t)(rowb + r) * N + col] =
                    acc[i][j][r] * scale + bb;
        }
    }
}

// ---------------------------------------------------------------- launch
extern "C" void kernel_launch(void* const* d_in, const int* in_sizes, int n_in,
                              void* d_out, int out_size, void* d_ws, size_t ws_size,
                              hipStream_t stream) {
    const int B = 4, S = 2048, E = 1024;
    const size_t SBE = (size_t)B * S * E;   // 8,388,608
    const size_t EE = (size_t)E * E;        // 1,048,576
    const size_t BSS = (size_t)B * S * S;   // 16,777,216

    const float* q_in = (const float*)d_in[0];
    const float* k_in = (const float*)d_in[1];
    const float* v_in = (const float*)d_in[2];
    // d_in[3] = mask (tril) — causality handled by index math
    const float* Wq = (const float*)d_in[4];
    const float* bq = (const float*)d_in[5];
    const float* Wk = (const float*)d_in[6];
    const float* bk = (const float*)d_in[7];
    const float* Wv = (const float*)d_in[8];
    const float* bv = (const float*)d_in[9];
    const float* Wo = (const float*)d_in[10];
    const float* bo = (const float*)d_in[11];

    char* ws = (char*)d_ws;
    bf16* QKVb = (bf16*)ws;                                  // 48 MB Qb|Kb|VW
    bf16* VWt  = (bf16*)(ws + 3 * SBE * 2);                  // 16 MB
    bf16* Sc   = (bf16*)(ws + 4 * SBE * 2);                  // 33.5 MB
    bf16* Pb   = (bf16*)(ws + 4 * SBE * 2 + BSS * 2);        // 33.5 MB
    bf16* Wb   = (bf16*)(ws + 4 * SBE * 2 + 2 * BSS * 2);    // 8 MB
    bf16* WvT  = Wb + 4 * EE;                                // 2 MB
    float* bout = (float*)(WvT + EE);                        // 4 KB

    bf16* Qb = QKVb;
    bf16* Kb = QKVb + SBE;
    bf16* VW = QKVb + 2 * SBE;
    bf16* Wob = Wb + 3 * EE;
    bf16* Wvo = Wb + 2 * EE;   // Wv slot overwritten by Wvo after transpose

    dim3 blk(256);

    // 1. weight converts (activations consumed as f32 by gemm_projf)
    dim3 gcvt4((int)(EE / 4 / 256), 1, 4);
    cvt4_f32_to_bf16<<<gcvt4, blk, 0, stream>>>(Wq, Wk, Wv, Wo, Wb, (int)(EE / 4));

    // 2. WvT = Wv^T ; Wvo = Wo @ Wv ; bout = Wo bv + bo
    dim3 gtw(16, 16, 1);
    transpose_bf16<<<gtw, blk, 0, stream>>>((const unsigned short*)(Wb + 2 * EE),
                                            (unsigned short*)WvT, E, E);
    dim3 gwvo(E / 128, E / 128, 1);
    gemm_bt128<<<gwvo, blk, 0, stream>>>(Wob, WvT, Wvo, E, E, E);
    bias_fold<<<256, blk, 0, stream>>>(Wo, bv, bo, bout);

    // 3. fused projections from f32 inputs (T14 split): Q, K, VW = v @ Wvo^T
    dim3 gproj(E / 128, (B * S) / 128, 3);
    gemm_projf<<<gproj, blk, 0, stream>>>(q_in, k_in, v_in, Wb, bq, bk,
                                          QKVb, B * S, E, E);

    // 4. VW^T per batch: [S,E] -> [E,S]
    dim3 gt(E / 64, S / 64, B);
    transpose_bf16<<<gt, blk, 0, stream>>>((const unsigned short*)VW,
                                           (unsigned short*)VWt, S, E);

    // 5. scores = Q K^T / 32 -> Sc bf16 (128x128 tiles, causal skip, bal)
    dim3 gsc(S / 128, S / 128, B);
    gemm_sc128<<<gsc, blk, 0, stream>>>(Qb, Kb, Sc, S, E);

    // 6. causal softmax -> bf16 probs (zeros above diagonal)
    softmax_causal<<<B * S, blk, 0, stream>>>(Sc, Pb, S);

    // 7. out = P @ VW + bout, causal K-trim (Keff = m0+128), 2 blocks/CU,
    //    XCD-pair-balanced
    dim3 gpv(E / 128, S / 128, B);
    gemm_pv128<<<gpv, blk, 0, stream>>>(Pb, VWt, bout, (float*)d_out, S, E, S,
                                        (long long)S * S, (long long)E * S,
                                        (long long)S * E, 1.f);
}

// Round 8
// 390.905 us; speedup vs baseline: 1.0984x; 1.0201x over previous
//
#include <hip/hip_runtime.h>

typedef __bf16 bf16;
typedef __attribute__((ext_vector_type(8))) __bf16 bf16x8;
typedef __attribute__((ext_vector_type(4))) __bf16 bf16x4;
typedef __attribute__((ext_vector_type(2))) __bf16 bf16x2;
typedef __attribute__((ext_vector_type(4))) float f32x4;

#define DEVINL __device__ __forceinline__

// Async global->LDS, 16B per lane.
DEVINL void gload_lds16(const bf16* g, bf16* l) {
    __builtin_amdgcn_global_load_lds(
        (__attribute__((address_space(1))) unsigned int*)(unsigned long long)g,
        (__attribute__((address_space(3))) unsigned int*)l,
        16, 0, 0);
}

// XCD-aware swizzle (uniform work): contiguous by-slab per XCD, bx fastest.
// Requires gridDim.y % 8 == 0.
DEVINL void xcd_swizzle(int& bx, int& by) {
    const int gx = gridDim.x, gy = gridDim.y;
    const int l = blockIdx.y * gx + blockIdx.x;
    const int xcd = l & 7;
    const int li = l >> 3;
    by = xcd * (gy >> 3) + li / gx;
    bx = li - (li / gx) * gx;
}

// Balanced XCD swizzle for causal grids (work ∝ by+1), gridDim.y==16 only:
// XCD x owns by = x and by = 15-x  ->  equal live work per XCD.
DEVINL void xcd_swizzle_bal(int& bx, int& by) {
    const int gx = gridDim.x, gy = gridDim.y;
    const int l = blockIdx.y * gx + blockIdx.x;
    const int xcd = l & 7;
    const int li = l >> 3;
    const int j = li / gx;            // slab 0 or 1
    bx = li - j * gx;
    by = j ? (gy - 1 - xcd) : xcd;
}

// ---------------------------------------------------------------- converts
// Weights Wq, Wk, Wo -> bf16 (slots 0, 1, 3 of Wb).  Wv goes through the
// fused transpose-convert below; slot 2 is reserved for Wvo.
__global__ __launch_bounds__(256) void cvt3w_f32_to_bf16(
    const float* __restrict__ a, const float* __restrict__ b,
    const float* __restrict__ c, bf16* __restrict__ out, int n4) {
    int i = blockIdx.x * blockDim.x + threadIdx.x;
    if (i >= n4) return;
    const float* src = (blockIdx.z == 0) ? a : (blockIdx.z == 1) ? b : c;
    const int slot = (blockIdx.z == 2) ? 3 : blockIdx.z;
    bf16* dst = out + (size_t)slot * (size_t)n4 * 4;
    float4 f = ((const float4*)src)[i];
    bf16x4 o;
    o.x = (bf16)f.x; o.y = (bf16)f.y; o.z = (bf16)f.z; o.w = (bf16)f.w;
    ((bf16x4*)dst)[i] = o;
}

// Fused transpose+convert: f32 [R][C] -> bf16 [C][R] (for WvT).
__global__ __launch_bounds__(256) void transcvt_f32_bf16(
    const float* __restrict__ in, bf16* __restrict__ out, int R, int C) {
    __shared__ float t[64][65];
    const int r0 = blockIdx.y * 64, c0 = blockIdx.x * 64;
    const int tr = threadIdx.x >> 4;      // 0..15
    const int tc = threadIdx.x & 15;      // 0..15
#pragma unroll
    for (int i = 0; i < 4; i++) {
        int r = tr + i * 16;
        float4 v = *(const float4*)&in[(size_t)(r0 + r) * C + (c0 + tc * 4)];
        t[r][tc * 4 + 0] = v.x; t[r][tc * 4 + 1] = v.y;
        t[r][tc * 4 + 2] = v.z; t[r][tc * 4 + 3] = v.w;
    }
    __syncthreads();
#pragma unroll
    for (int i = 0; i < 4; i++) {
        int r = tr + i * 16;
        bf16x4 o;
        o.x = (bf16)t[tc * 4 + 0][r]; o.y = (bf16)t[tc * 4 + 1][r];
        o.z = (bf16)t[tc * 4 + 2][r]; o.w = (bf16)t[tc * 4 + 3][r];
        *(bf16x4*)&out[(size_t)(c0 + r) * R + (r0 + tc * 4)] = o;
    }
}

// ---------------------------------------------------------------- transpose
__global__ __launch_bounds__(256) void transpose_bf16(
    const unsigned short* __restrict__ in, unsigned short* __restrict__ out,
    int R, int C) {
    __shared__ unsigned short t[64][65];
    const size_t bo = (size_t)blockIdx.z * R * C;
    const int r0 = blockIdx.y * 64, c0 = blockIdx.x * 64;
    const int tr = threadIdx.x >> 4;      // 0..15
    const int tc = threadIdx.x & 15;      // 0..15
#pragma unroll
    for (int i = 0; i < 4; i++) {
        int r = tr + i * 16;
        ushort4 v = *(const ushort4*)&in[bo + (size_t)(r0 + r) * C + (c0 + tc * 4)];
        t[r][tc * 4 + 0] = v.x; t[r][tc * 4 + 1] = v.y;
        t[r][tc * 4 + 2] = v.z; t[r][tc * 4 + 3] = v.w;
    }
    __syncthreads();
#pragma unroll
    for (int i = 0; i < 4; i++) {
        int r = tr + i * 16;              // output row = original col
        ushort4 v;
        v.x = t[tc * 4 + 0][r]; v.y = t[tc * 4 + 1][r];
        v.z = t[tc * 4 + 2][r]; v.w = t[tc * 4 + 3][r];
        *(ushort4*)&out[bo + (size_t)(c0 + r) * R + (r0 + tc * 4)] = v;
    }
}

// ---------------------------------------------------------------- bias fold
// bout[e] = dot(Wo[e,:], bv) + bo[e]   (one wave per e)
__global__ __launch_bounds__(256) void bias_fold(
    const float* __restrict__ Wo, const float* __restrict__ bv,
    const float* __restrict__ bo, float* __restrict__ bout) {
    const int e = blockIdx.x * 4 + (threadIdx.x >> 6);
    const int lane = threadIdx.x & 63;
    float s = 0.f;
    for (int k = lane; k < 1024; k += 64) s += Wo[e * 1024 + k] * bv[k];
#pragma unroll
    for (int off = 32; off > 0; off >>= 1) s += __shfl_xor(s, off, 64);
    if (lane == 0) bout[e] = s + bo[e];
}

// ------------------------------- GEMM 128x128, BK=32, LDS dbuf + XOR swizzle
// (small Wvo = Wo @ Wv 1024^3 GEMM; bf16 A)
__global__ __launch_bounds__(256) void gemm_bt128(
    const bf16* __restrict__ A, const bf16* __restrict__ B,
    bf16* __restrict__ C, int M, int N, int K) {
    int bx, by;
    xcd_swizzle(bx, by);
    const int m0 = by * 128, n0 = bx * 128;

    __shared__ __align__(16) bf16 As[2][128 * 32];
    __shared__ __align__(16) bf16 Bs[2][128 * 32];

    const int tid = threadIdx.x;
    const int wave = tid >> 6;
    const int lane = tid & 63;
    const int lr = lane & 15;
    const int lq = lane >> 4;
    const int wm = (wave >> 1) * 64;
    const int wn = (wave & 1) * 64;
    const int srow = lane >> 2;
    const int scol = ((lane & 3) ^ ((lane >> 3) & 3)) * 8;

    const bf16* gA = A + (size_t)(m0 + wave * 16 + srow) * K + scol;
    const bf16* gB = B + (size_t)(n0 + wave * 16 + srow) * K + scol;
    const size_t rowskip = (size_t)64 * K;
    const int rsw = (lq ^ ((lr >> 1) & 3)) * 8;

    f32x4 acc[4][4];
    const f32x4 fzero = {0.f, 0.f, 0.f, 0.f};
#pragma unroll
    for (int i = 0; i < 4; i++)
#pragma unroll
        for (int j = 0; j < 4; j++) acc[i][j] = fzero;

#define STAGE128(bufi)                                          \
    do {                                                        \
        gload_lds16(gA,           As[bufi] + wave * 512);       \
        gload_lds16(gA + rowskip, As[bufi] + (wave + 4) * 512); \
        gload_lds16(gB,           Bs[bufi] + wave * 512);       \
        gload_lds16(gB + rowskip, Bs[bufi] + (wave + 4) * 512); \
        gA += 32; gB += 32;                                     \
    } while (0)

    STAGE128(0);
    int cur = 0;
    for (int k0 = 0; k0 < K; k0 += 32) {
        __syncthreads();
        if (k0 + 32 < K) STAGE128(cur ^ 1);

        bf16x8 af[4], bfr[4];
#pragma unroll
        for (int i = 0; i < 4; i++)
            af[i] = *(const bf16x8*)(As[cur] + (wm + i * 16 + lr) * 32 + rsw);
#pragma unroll
        for (int j = 0; j < 4; j++)
            bfr[j] = *(const bf16x8*)(Bs[cur] + (wn + j * 16 + lr) * 32 + rsw);
#pragma unroll
        for (int i = 0; i < 4; i++)
#pragma unroll
            for (int j = 0; j < 4; j++)
                acc[i][j] = __builtin_amdgcn_mfma_f32_16x16x32_bf16(
                    af[i], bfr[j], acc[i][j], 0, 0, 0);
        cur ^= 1;
    }
#undef STAGE128

#pragma unroll
    for (int j = 0; j < 4; j++) {
        const int col = n0 + wn + j * 16 + lr;
#pragma unroll
        for (int i = 0; i < 4; i++) {
            const int rowb = m0 + wm + i * 16 + lq * 4;
#pragma unroll
            for (int r = 0; r < 4; r++)
                C[(size_t)(rowb + r) * N + col] = (bf16)acc[i][j][r];
        }
    }
}

// ---------------- Projection GEMM 128x128, BK=32, 2-buf; A read as f32.
// T14 split with TOP-OF-BODY load issue + double register sets:
//   iter t: ISSUE f32 loads A(t+2) (earliest -> full body before the
//   end-of-iter vmcnt(0) drain, like round-0's DMA position) ;
//   frag ds_reads(cur) ; cvt+ds_write A(t+1) from the OTHER reg set
//   (loaded at t-1, drained by t-1's barrier) ; B(t+1) DMA ; MFMA ; sync.
// 2-iteration unroll keeps reg-set indexing static (no scratch).
// LDS image identical to the DMA path. z=0:Q+bq z=1:K+bk z=2:VW.
__global__ __launch_bounds__(256) void gemm_projf(
    const float* __restrict__ A0, const float* __restrict__ A1,
    const float* __restrict__ A2, const bf16* __restrict__ Bw,
    const float* __restrict__ bias0, const float* __restrict__ bias1,
    bf16* __restrict__ Cq, int M, int N, int K) {
    int bx, by;
    xcd_swizzle(bx, by);
    const int bz = blockIdx.z;
    const int m0 = by * 128, n0 = bx * 128;

    const float* Af = (bz == 0) ? A0 : (bz == 1) ? A1 : A2;
    const bf16* B = Bw + (size_t)bz * (size_t)N * K;
    const float* bias = (bz == 0) ? bias0 : (bz == 1) ? bias1 : nullptr;
    bf16* C = Cq + (size_t)bz * (size_t)M * N;

    __shared__ __align__(16) bf16 As[2][128 * 32];
    __shared__ __align__(16) bf16 Bs[2][128 * 32];

    const int tid = threadIdx.x;
    const int wave = tid >> 6;
    const int lane = tid & 63;
    const int lr = lane & 15;
    const int lq = lane >> 4;
    const int wm = (wave >> 1) * 64;
    const int wn = (wave & 1) * 64;
    const int srow = lane >> 2;                       // 0..15
    const int gsrc = (lane & 3) ^ ((lane >> 3) & 3);  // pre-swizzled granule

    const float* fA = Af + (size_t)(m0 + wave * 16 + srow) * K + gsrc * 8;
    const bf16*  gB = B + (size_t)(n0 + wave * 16 + srow) * K + gsrc * 8;
    const size_t rsA = (size_t)64 * K;
    const size_t rsB = (size_t)64 * K;
    const int rsw = (lq ^ ((lr >> 1) & 3)) * 8;
    const int NT = K >> 5;    // 32 (even)

    f32x4 acc[4][4];
    const f32x4 fzero = {0.f, 0.f, 0.f, 0.f};
#pragma unroll
    for (int i = 0; i < 4; i++)
#pragma unroll
        for (int j = 0; j < 4; j++) acc[i][j] = fzero;

    // two in-flight A register sets (one tile each)
    float4 xa0, xa1, xa2, xa3;   // set X
    float4 ya0, ya1, ya2, ya3;   // set Y

#define LOADA_(s0, s1, s2, s3, kt)                                        \
    do {                                                                  \
        const float* p_ = fA + (size_t)(kt) * 32;                         \
        s0 = *(const float4*)(p_);                                        \
        s1 = *(const float4*)(p_ + 4);                                    \
        s2 = *(const float4*)(p_ + rsA);                                  \
        s3 = *(const float4*)(p_ + rsA + 4);                              \
    } while (0)
#define WRITEA_(s0, s1, s2, s3, bufi)                                     \
    do {                                                                  \
        bf16x8 p0, p1;                                                    \
        p0[0] = (bf16)s0.x; p0[1] = (bf16)s0.y;                           \
        p0[2] = (bf16)s0.z; p0[3] = (bf16)s0.w;                           \
        p0[4] = (bf16)s1.x; p0[5] = (bf16)s1.y;                           \
        p0[6] = (bf16)s1.z; p0[7] = (bf16)s1.w;                           \
        p1[0] = (bf16)s2.x; p1[1] = (bf16)s2.y;                           \
        p1[2] = (bf16)s2.z; p1[3] = (bf16)s2.w;                           \
        p1[4] = (bf16)s3.x; p1[5] = (bf16)s3.y;                           \
        p1[6] = (bf16)s3.z; p1[7] = (bf16)s3.w;                           \
        *(bf16x8*)(As[bufi] + wave * 512 + lane * 8) = p0;                \
        *(bf16x8*)(As[bufi] + (wave + 4) * 512 + lane * 8) = p1;          \
    } while (0)
#define STAGEB(bufi, kt)                                                  \
    do {                                                                  \
        gload_lds16(gB + (size_t)(kt) * 32,       Bs[bufi] + wave * 512); \
        gload_lds16(gB + rsB + (size_t)(kt) * 32, Bs[bufi] + (wave + 4) * 512); \
    } while (0)
#define FRAGS(bufi)                                                       \
    do {                                                                  \
        _Pragma("unroll")                                                 \
        for (int i = 0; i < 4; i++)                                       \
            af[i] = *(const bf16x8*)(As[bufi] + (wm + i * 16 + lr) * 32 + rsw); \
        _Pragma("unroll")                                                 \
        for (int j = 0; j < 4; j++)                                       \
            bfr[j] = *(const bf16x8*)(Bs[bufi] + (wn + j * 16 + lr) * 32 + rsw); \
    } while (0)
#define MFMA16()                                                          \
    do {                                                                  \
        _Pragma("unroll")                                                 \
        for (int i = 0; i < 4; i++)                                       \
            _Pragma("unroll")                                             \
            for (int j = 0; j < 4; j++)                                   \
                acc[i][j] = __builtin_amdgcn_mfma_f32_16x16x32_bf16(      \
                    af[i], bfr[j], acc[i][j], 0, 0, 0);                   \
    } while (0)

    // prologue: A(0) via set X -> LDS, B(0) DMA, A(1) issued into set Y;
    // the barrier drains both the DMA and the set-Y loads.
    LOADA_(xa0, xa1, xa2, xa3, 0);
    STAGEB(0, 0);
    WRITEA_(xa0, xa1, xa2, xa3, 0);   // waits set-X loads (once)
    LOADA_(ya0, ya1, ya2, ya3, 1);
    __syncthreads();

    for (int tt = 0; tt < NT; tt += 2) {
        // ---- even iter: t = tt, cur = 0 -------------------------------
        {
            const int t = tt;
            if (t + 2 < NT) LOADA_(xa0, xa1, xa2, xa3, t + 2);  // issue first
            bf16x8 af[4], bfr[4];
            FRAGS(0);
            if (t + 1 < NT) {
                WRITEA_(ya0, ya1, ya2, ya3, 1);   // A(t+1), resident
                STAGEB(1, t + 1);                 // B(t+1) DMA
            }
            MFMA16();
            __syncthreads();
        }
        // ---- odd iter: t = tt+1, cur = 1 ------------------------------
        {
            const int t = tt + 1;
            if (t + 2 < NT) LOADA_(ya0, ya1, ya2, ya3, t + 2);  // issue first
            bf16x8 af[4], bfr[4];
            FRAGS(1);
            if (t + 1 < NT) {
                WRITEA_(xa0, xa1, xa2, xa3, 0);   // A(t+1), resident
                STAGEB(0, t + 1);                 // B(t+1) DMA
            }
            MFMA16();
            __syncthreads();
        }
    }
#undef LOADA_
#undef WRITEA_
#undef STAGEB
#undef FRAGS
#undef MFMA16

#pragma unroll
    for (int j = 0; j < 4; j++) {
        const int col = n0 + wn + j * 16 + lr;
        const float bb = bias ? bias[col] : 0.0f;
#pragma unroll
        for (int i = 0; i < 4; i++) {
            const int rowb = m0 + wm + i * 16 + lq * 4;
#pragma unroll
            for (int r = 0; r < 4; r++)
                C[(size_t)(rowb + r) * N + col] = (bf16)(acc[i][j][r] + bb);
        }
    }
}

// ---------------- Scores GEMM 128x128 (proven bt128 body) + causal skip.
// Sc = Q K^T / 32 (bf16 raw; softmax handles masking). 544 live blocks of
// 1024; balanced XCD swizzle (gy=16) pairs by=x with by=15-x.
__global__ __launch_bounds__(256) void gemm_sc128(
    const bf16* __restrict__ Qb, const bf16* __restrict__ Kb,
    bf16* __restrict__ Sc, int S, int E) {
    int bx, by;
    xcd_swizzle_bal(bx, by);
    const int bz = blockIdx.z;
    const int m0 = by * 128, n0 = bx * 128;
    if (n0 > m0 + 127) return;   // fully above diagonal

    const bf16* A = Qb + (size_t)bz * S * E;
    const bf16* B = Kb + (size_t)bz * S * E;

    __shared__ __align__(16) bf16 As[2][128 * 32];
    __shared__ __align__(16) bf16 Bs[2][128 * 32];

    const int tid = threadIdx.x;
    const int wave = tid >> 6;
    const int lane = tid & 63;
    const int lr = lane & 15;
    const int lq = lane >> 4;
    const int wm = (wave >> 1) * 64;
    const int wn = (wave & 1) * 64;
    const int srow = lane >> 2;
    const int scol = ((lane & 3) ^ ((lane >> 3) & 3)) * 8;

    const bf16* gA = A + (size_t)(m0 + wave * 16 + srow) * E + scol;
    const bf16* gB = B + (size_t)(n0 + wave * 16 + srow) * E + scol;
    const size_t rowskip = (size_t)64 * E;
    const int rsw = (lq ^ ((lr >> 1) & 3)) * 8;

    f32x4 acc[4][4];
    const f32x4 fzero = {0.f, 0.f, 0.f, 0.f};
#pragma unroll
    for (int i = 0; i < 4; i++)
#pragma unroll
        for (int j = 0; j < 4; j++) acc[i][j] = fzero;

#define STAGESC(bufi)                                           \
    do {                                                        \
        gload_lds16(gA,           As[bufi] + wave * 512);       \
        gload_lds16(gA + rowskip, As[bufi] + (wave + 4) * 512); \
        gload_lds16(gB,           Bs[bufi] + wave * 512);       \
        gload_lds16(gB + rowskip, Bs[bufi] + (wave + 4) * 512); \
        gA += 32; gB += 32;                                     \
    } while (0)

    STAGESC(0);
    int cur = 0;
    for (int k0 = 0; k0 < E; k0 += 32) {
        __syncthreads();
        if (k0 + 32 < E) STAGESC(cur ^ 1);

        bf16x8 af[4], bfr[4];
#pragma unroll
        for (int i = 0; i < 4; i++)
            af[i] = *(const bf16x8*)(As[cur] + (wm + i * 16 + lr) * 32 + rsw);
#pragma unroll
        for (int j = 0; j < 4; j++)
            bfr[j] = *(const bf16x8*)(Bs[cur] + (wn + j * 16 + lr) * 32 + rsw);
#pragma unroll
        for (int i = 0; i < 4; i++)
#pragma unroll
            for (int j = 0; j < 4; j++)
                acc[i][j] = __builtin_amdgcn_mfma_f32_16x16x32_bf16(
                    af[i], bfr[j], acc[i][j], 0, 0, 0);
        cur ^= 1;
    }
#undef STAGESC

    bf16* dst = Sc + (size_t)bz * S * S;
#pragma unroll
    for (int j = 0; j < 4; j++) {
        const int col = n0 + wn + j * 16 + lr;
#pragma unroll
        for (int i = 0; i < 4; i++) {
            const int rowb = m0 + wm + i * 16 + lq * 4;
#pragma unroll
            for (int r = 0; r < 4; r++)
                dst[(size_t)(rowb + r) * S + col] =
                    (bf16)(acc[i][j][r] * 0.03125f);
        }
    }
}

// ---------------------------------------------------------------- softmax
__global__ __launch_bounds__(256) void softmax_causal(
    const bf16* __restrict__ Sc, bf16* __restrict__ P, int S) {
    const int row = blockIdx.x;          // b*S + q
    const int q = row & (S - 1);
    const bf16* src = Sc + (size_t)row * S;
    bf16* dst = P + (size_t)row * S;
    const int L = q + 1;
    const int tid = threadIdx.x;
    const int k0 = tid * 8;

    bf16x8 u = ((const bf16x8*)src)[tid];
    float v[8];
    float mx = -3.0e38f;
#pragma unroll
    for (int i = 0; i < 8; i++) {
        v[i] = (k0 + i < L) ? (float)u[i] : -3.0e38f;
        mx = fmaxf(mx, v[i]);
    }
#pragma unroll
    for (int off = 32; off > 0; off >>= 1) mx = fmaxf(mx, __shfl_xor(mx, off, 64));
    __shared__ float redm[4], reds[4];
    if ((tid & 63) == 0) redm[tid >> 6] = mx;
    __syncthreads();
    mx = fmaxf(fmaxf(redm[0], redm[1]), fmaxf(redm[2], redm[3]));

    float sum = 0.f;
#pragma unroll
    for (int i = 0; i < 8; i++) {
        float e = (v[i] > -1.0e38f) ? __expf(v[i] - mx) : 0.f;
        v[i] = e;
        sum += e;
    }
#pragma unroll
    for (int off = 32; off > 0; off >>= 1) sum += __shfl_xor(sum, off, 64);
    if ((tid & 63) == 0) reds[tid >> 6] = sum;
    __syncthreads();
    sum = reds[0] + reds[1] + reds[2] + reds[3];
    const float inv = 1.0f / sum;
    bf16x8 o;
#pragma unroll
    for (int i = 0; i < 8; i++) o[i] = (bf16)(v[i] * inv);
    ((bf16x8*)dst)[tid] = o;
}

// ---------------- GEMM 128x128, BK=32, 256 thr, 4-buf template-phase pipe
// (proven round 3/4/6/7). 64 KiB LDS -> 2 blocks/CU so causal K-trimmed
// blocks pair on a CU. PV: Keff = m0+128; balanced pair swizzle.
__global__ __launch_bounds__(256, 2) void gemm_pv128(
    const bf16* __restrict__ A, const bf16* __restrict__ B,
    const float* __restrict__ bias, float* __restrict__ C,
    int M, int N, int K,
    long long sA, long long sB, long long sC,
    float scale) {
    int bx, by;
    xcd_swizzle_bal(bx, by);
    const int bz = blockIdx.z;
    const int m0 = by * 128, n0 = bx * 128;
    int Keff = m0 + 128; if (Keff > K) Keff = K;
    const int NT = Keff >> 5;   // >= 4

    A += (size_t)bz * sA;
    B += (size_t)bz * sB;

    __shared__ __align__(16) bf16 As[4][128 * 32];
    __shared__ __align__(16) bf16 Bs[4][128 * 32];

    const int tid = threadIdx.x;
    const int wave = tid >> 6;            // 0..3
    const int lane = tid & 63;
    const int lr = lane & 15;
    const int lq = lane >> 4;
    const int wm = (wave >> 1) * 64;
    const int wn = (wave & 1) * 64;

    const int srow = lane >> 2;
    const int scol = ((lane & 3) ^ ((lane >> 3) & 3)) * 8;
    const bf16* gA = A + (size_t)(m0 + wave * 16 + srow) * K + scol;
    const bf16* gB = B + (size_t)(n0 + wave * 16 + srow) * K + scol;
    const size_t rowskip = (size_t)64 * K;

    const int rsw = (lq ^ ((lr >> 1) & 3)) * 8;

    f32x4 acc[4][4];
    const f32x4 fzero = {0.f, 0.f, 0.f, 0.f};
#pragma unroll
    for (int i = 0; i < 4; i++)
#pragma unroll
        for (int j = 0; j < 4; j++) acc[i][j] = fzero;

#define STAGEV(bufi, koff)                                                 \
    do {                                                                   \
        gload_lds16(gA + (koff),           As[bufi] + wave * 512);         \
        gload_lds16(gA + rowskip + (koff), As[bufi] + (wave + 4) * 512);   \
        gload_lds16(gB + (koff),           Bs[bufi] + wave * 512);         \
        gload_lds16(gB + rowskip + (koff), Bs[bufi] + (wave + 4) * 512);   \
    } while (0)

    STAGEV(0, 0);
    STAGEV(1, 32);
    STAGEV(2, 64);
    asm volatile("s_waitcnt vmcnt(8)" ::: "memory");
    __builtin_amdgcn_s_barrier();

    for (int t = 0; t < NT; ++t) {
        const int bfi = t & 3;

        bf16x8 af[4], bfr[4];
#pragma unroll
        for (int i = 0; i < 4; i++)
            af[i] = *(const bf16x8*)(As[bfi] + (wm + i * 16 + lr) * 32 + rsw);
#pragma unroll
        for (int j = 0; j < 4; j++)
            bfr[j] = *(const bf16x8*)(Bs[bfi] + (wn + j * 16 + lr) * 32 + rsw);

        if (t + 3 < NT) STAGEV((t + 3) & 3, (t + 3) * 32);

        const int rem = NT - 1 - t;
        if (rem >= 3)      asm volatile("s_waitcnt vmcnt(8)" ::: "memory");
        else if (rem == 2) asm volatile("s_waitcnt vmcnt(4)" ::: "memory");
        else if (rem == 1) asm volatile("s_waitcnt vmcnt(0)" ::: "memory");
        __builtin_amdgcn_s_barrier();
        __builtin_amdgcn_sched_barrier(0);

        __builtin_amdgcn_s_setprio(1);
#pragma unroll
        for (int i = 0; i < 4; i++)
#pragma unroll
            for (int j = 0; j < 4; j++)
                acc[i][j] = __builtin_amdgcn_mfma_f32_16x16x32_bf16(
                    af[i], bfr[j], acc[i][j], 0, 0, 0);
        __builtin_amdgcn_s_setprio(0);
        __builtin_amdgcn_s_barrier();
    }
#undef STAGEV

#pragma unroll
    for (int j = 0; j < 4; j++) {
        const int col = n0 + wn + j * 16 + lr;
        const float bb = bias[col];
#pragma unroll
        for (int i = 0; i < 4; i++) {
            const int rowb = m0 + wm + i * 16 + lq * 4;
#pragma unroll
            for (int r = 0; r < 4; r++)
                C[(size_t)bz * sC + (size_t)(rowb + r) * N + col] =
                    acc[i][j][r] * scale + bb;
        }
    }
}

// ---------------------------------------------------------------- launch
extern "C" void kernel_launch(void* const* d_in, const int* in_sizes, int n_in,
                              void* d_out, int out_size, void* d_ws, size_t ws_size,
                              hipStream_t stream) {
    const int B = 4, S = 2048, E = 1024;
    const size_t SBE = (size_t)B * S * E;   // 8,388,608
    const size_t EE = (size_t)E * E;        // 1,048,576
    const size_t BSS = (size_t)B * S * S;   // 16,777,216

    const float* q_in = (const float*)d_in[0];
    const float* k_in = (const float*)d_in[1];
    const float* v_in = (const float*)d_in[2];
    // d_in[3] = mask (tril) — causality handled by index math
    const float* Wq = (const float*)d_in[4];
    const float* bq = (const float*)d_in[5];
    const float* Wk = (const float*)d_in[6];
    const float* bk = (const float*)d_in[7];
    const float* Wv = (const float*)d_in[8];
    const float* bv = (const float*)d_in[9];
    const float* Wo = (const float*)d_in[10];
    const float* bo = (const float*)d_in[11];

    char* ws = (char*)d_ws;
    bf16* QKVb = (bf16*)ws;                                  // 48 MB Qb|Kb|VW
    bf16* VWt  = (bf16*)(ws + 3 * SBE * 2);                  // 16 MB
    bf16* Sc   = (bf16*)(ws + 4 * SBE * 2);                  // 33.5 MB
    bf16* Pb   = (bf16*)(ws + 4 * SBE * 2 + BSS * 2);        // 33.5 MB
    bf16* Wb   = (bf16*)(ws + 4 * SBE * 2 + 2 * BSS * 2);    // 8 MB
    bf16* WvT  = Wb + 4 * EE;                                // 2 MB
    float* bout = (float*)(WvT + EE);                        // 4 KB

    bf16* Qb = QKVb;
    bf16* Kb = QKVb + SBE;
    bf16* VW = QKVb + 2 * SBE;
    bf16* Wob = Wb + 3 * EE;
    bf16* Wvo = Wb + 2 * EE;   // slot 2 holds Wvo (Wv bf16 never materialized)

    dim3 blk(256);

    // 1. weight converts: Wq, Wk, Wo -> bf16 slots 0,1,3; Wv -> WvT fused
    dim3 gcvt3((int)(EE / 4 / 256), 1, 3);
    cvt3w_f32_to_bf16<<<gcvt3, blk, 0, stream>>>(Wq, Wk, Wo, Wb, (int)(EE / 4));
    dim3 gtw(16, 16, 1);
    transcvt_f32_bf16<<<gtw, blk, 0, stream>>>(Wv, WvT, E, E);

    // 2. Wvo = Wo @ Wv ; bout = Wo bv + bo
    dim3 gwvo(E / 128, E / 128, 1);
    gemm_bt128<<<gwvo, blk, 0, stream>>>(Wob, WvT, Wvo, E, E, E);
    bias_fold<<<256, blk, 0, stream>>>(Wo, bv, bo, bout);

    // 3. fused projections from f32 inputs (T14, top-issued loads):
    //    Q, K, VW = v @ Wvo^T
    dim3 gproj(E / 128, (B * S) / 128, 3);
    gemm_projf<<<gproj, blk, 0, stream>>>(q_in, k_in, v_in, Wb, bq, bk,
                                          QKVb, B * S, E, E);

    // 4. VW^T per batch: [S,E] -> [E,S]
    dim3 gt(E / 64, S / 64, B);
    transpose_bf16<<<gt, blk, 0, stream>>>((const unsigned short*)VW,
                                           (unsigned short*)VWt, S, E);

    // 5. scores = Q K^T / 32 -> Sc bf16 (128x128 tiles, causal skip, bal)
    dim3 gsc(S / 128, S / 128, B);
    gemm_sc128<<<gsc, blk, 0, stream>>>(Qb, Kb, Sc, S, E);

    // 6. causal softmax -> bf16 probs (zeros above diagonal)
    softmax_causal<<<B * S, blk, 0, stream>>>(Sc, Pb, S);

    // 7. out = P @ VW + bout, causal K-trim (Keff = m0+128), 2 blocks/CU,
    //    XCD-pair-balanced
    dim3 gpv(E / 128, S / 128, B);
    gemm_pv128<<<gpv, blk, 0, stream>>>(Pb, VWt, bout, (float*)d_out, S, E, S,
                                        (long long)S * S, (long long)E * S,
                                        (long long)S * E, 1.f);
}